// Round 1
// baseline (46540.579 us; speedup 1.0000x reference)
//
#include <hip/hip_runtime.h>
#include <math.h>

namespace {
constexpr int Bn = 128, Ln = 256, En = 512, Hn = 512;

// ws layout (float offsets)
constexpr long WS_CTX  = 1024;                       // [B][L][H] = ctx[b,l,o]
constexpr long WS_H    = WS_CTX + (long)Bn * Ln * Hn;
constexpr long WS_C    = WS_H   + (long)Bn * Hn;
constexpr long WS_HL   = WS_C   + (long)Bn * Hn;
constexpr long WS_DEC  = WS_HL  + (long)Bn * Hn;

// out layout (float offsets)
constexpr long OUT_PTR = (long)Bn * Ln * Ln;   // 8388608
constexpr long OUT_HF  = OUT_PTR + (long)Bn * Ln;
constexpr long OUT_CF  = OUT_HF + (long)Bn * Hn;
}

struct PParams {
  const float *emb, *dec0, *h0, *c0;
  const float *Wih, *bih, *Whh, *bhh;
  const float *Who, *bho, *Wa_in, *ba_in, *V;
  float *ws, *out;
};

// ------- sharded grid barrier (256 blocks = 4 shards x 64, 1 block/CU) ------
__device__ __forceinline__ void gsync(unsigned* ub, unsigned target, int blk) {
  __syncthreads();
  if (threadIdx.x == 0) {
    unsigned* shard  = ub + (blk & 3) * 64;   // 256B apart
    unsigned* master = ub + 512;
    unsigned* gen    = ub + 576;
    bool released = false;
    unsigned n = __hip_atomic_fetch_add(shard, 1u, __ATOMIC_ACQ_REL, __HIP_MEMORY_SCOPE_AGENT);
    if (n == 63u) {
      __hip_atomic_store(shard, 0u, __ATOMIC_RELAXED, __HIP_MEMORY_SCOPE_AGENT);
      unsigned mn = __hip_atomic_fetch_add(master, 1u, __ATOMIC_ACQ_REL, __HIP_MEMORY_SCOPE_AGENT);
      if (mn == 3u) {
        __hip_atomic_store(master, 0u, __ATOMIC_RELAXED, __HIP_MEMORY_SCOPE_AGENT);
        __hip_atomic_store(gen, target, __ATOMIC_RELEASE, __HIP_MEMORY_SCOPE_AGENT);
        released = true;
      }
    }
    if (!released) {
      while (__hip_atomic_load(gen, __ATOMIC_RELAXED, __HIP_MEMORY_SCOPE_AGENT) < target)
        __builtin_amdgcn_s_sleep(2);
      (void)__hip_atomic_load(gen, __ATOMIC_ACQUIRE, __HIP_MEMORY_SCOPE_AGENT);
    }
  }
  __syncthreads();
}

// ---------------- ctx precompute: ctx[b,l,o] = context[b,l,:]·Wa_ctx[o,:] + ba_ctx[o]
__launch_bounds__(256)
__global__ void ctx_precompute(const float* __restrict__ context,
                               const float* __restrict__ Wa,
                               const float* __restrict__ ba,
                               float* __restrict__ ws) {
  __shared__ __align__(16) float As[16 * 68];
  __shared__ __align__(16) float Wsm[16 * 68];
  float* ctx = ws + WS_CTX;
  const int mt = blockIdx.x >> 3;
  const int nt = blockIdx.x & 7;
  const int t = threadIdx.x;
  const int tm = t & 15, tn = t >> 4;
  float acc00=0,acc01=0,acc02=0,acc03=0, acc10=0,acc11=0,acc12=0,acc13=0;
  float acc20=0,acc21=0,acc22=0,acc23=0, acc30=0,acc31=0,acc32=0,acc33=0;

  for (int kt = 0; kt < 32; ++kt) {
    __syncthreads();
    {
      const int m = t >> 2, k4 = t & 3;
      float4 a = *(const float4*)(context + (size_t)(mt * 64 + m) * 512 + kt * 16 + k4 * 4);
      As[(k4*4+0)*68 + m] = a.x; As[(k4*4+1)*68 + m] = a.y;
      As[(k4*4+2)*68 + m] = a.z; As[(k4*4+3)*68 + m] = a.w;
      float4 w = *(const float4*)(Wa + (size_t)(nt * 64 + m) * 512 + kt * 16 + k4 * 4);
      Wsm[(k4*4+0)*68 + m] = w.x; Wsm[(k4*4+1)*68 + m] = w.y;
      Wsm[(k4*4+2)*68 + m] = w.z; Wsm[(k4*4+3)*68 + m] = w.w;
    }
    __syncthreads();
#pragma unroll
    for (int k = 0; k < 16; ++k) {
      float4 a4 = *(const float4*)(As + k * 68 + tm * 4);
      float4 b4 = *(const float4*)(Wsm + k * 68 + tn * 4);
      acc00 = fmaf(a4.x, b4.x, acc00); acc01 = fmaf(a4.x, b4.y, acc01);
      acc02 = fmaf(a4.x, b4.z, acc02); acc03 = fmaf(a4.x, b4.w, acc03);
      acc10 = fmaf(a4.y, b4.x, acc10); acc11 = fmaf(a4.y, b4.y, acc11);
      acc12 = fmaf(a4.y, b4.z, acc12); acc13 = fmaf(a4.y, b4.w, acc13);
      acc20 = fmaf(a4.z, b4.x, acc20); acc21 = fmaf(a4.z, b4.y, acc21);
      acc22 = fmaf(a4.z, b4.z, acc22); acc23 = fmaf(a4.z, b4.w, acc23);
      acc30 = fmaf(a4.w, b4.x, acc30); acc31 = fmaf(a4.w, b4.y, acc31);
      acc32 = fmaf(a4.w, b4.z, acc32); acc33 = fmaf(a4.w, b4.w, acc33);
    }
  }
  const int col = nt * 64 + tn * 4;
  float4 bias = *(const float4*)(ba + col);
  float4 o0 = {acc00 + bias.x, acc01 + bias.y, acc02 + bias.z, acc03 + bias.w};
  float4 o1 = {acc10 + bias.x, acc11 + bias.y, acc12 + bias.z, acc13 + bias.w};
  float4 o2 = {acc20 + bias.x, acc21 + bias.y, acc22 + bias.z, acc23 + bias.w};
  float4 o3 = {acc30 + bias.x, acc31 + bias.y, acc32 + bias.z, acc33 + bias.w};
  const size_t base = (size_t)(mt * 64 + tm * 4) * 512 + col;
  *(float4*)(ctx + base + 0 * 512) = o0;
  *(float4*)(ctx + base + 1 * 512) = o1;
  *(float4*)(ctx + base + 2 * 512) = o2;
  *(float4*)(ctx + base + 3 * 512) = o3;
}

// --------- persistent main loop: 256 blocks x 1024 threads (1/CU, 16 waves) --
// Restructured from the 5-barrier R2 kernel into 2 grid barriers/step:
//   Island A  (256 blocks, batched): gates GEMM + LSTM elementwise -> hl, c
//   Island BCEF (128 blocks, one per batch row): inp, att, softmax/argmax,
//               outputs, dec gather, hs, h_t  -- all LDS-resident, only
//               __syncthreads between sub-phases.
// Every per-output fma sequence / softmax tree / argmax tie rule / K-split
// combine is a bit-exact clone of the R2 kernel (which passed): only the
// thread/block assignment changed, never the value sequence.
__launch_bounds__(1024, 4)
__global__ void pdecoder_main(PParams p) {
  __shared__ __align__(16) float smem[8192];   // 32 KB
  // persistent regions (never touched by A's tile [0..5200) or island2 [0..3584))
  float* V_s    = smem + 7168;   // [512], constant V
  float* mask_s = smem + 7680;   // [256], per-b mask (block-local!)

  float* ws = p.ws;
  unsigned* ub = (unsigned*)ws;
  unsigned tgt = 0;
  const int t = threadIdx.x, blk = blockIdx.x;

  float* ctx    = ws + WS_CTX;
  float* hbuf   = ws + WS_H;
  float* cbuf   = ws + WS_C;
  float* hlbuf  = ws + WS_HL;
  float* decbuf = ws + WS_DEC;

  // ---- init state (ws poisoned every call) ----
  {
    int idx = blk * 1024 + t;
    if (idx < Bn * Hn) { hbuf[idx] = p.h0[idx]; cbuf[idx] = p.c0[idx]; }
    if (idx < Bn * En) decbuf[idx] = p.dec0[idx];
  }
  if (blk < Bn) {
    if (t < Hn) V_s[t] = p.V[t];
    if (t < Ln) mask_s[t] = 1.0f;
  }
  gsync(ub, ++tgt, blk);

  for (int step = 0; step < Ln; ++step) {
    // ===== Island A: gates = dec@Wih^T + h@Whh^T + b; LSTM elementwise ======
    // 256 blocks = 8 b-tiles(16) x 32 h-groups(16). One gate-output/thread,
    // K fully sequential (kt 0..3, k4 0..63, xyzw) — exact R2 per-output order.
    // 16-row staging tile: per-wave x-reads are 16-distinct + 4x broadcast
    // (<=2-way bank alias) instead of the 32-row 4-way pattern; staging load
    // is prefetched one tile ahead.
    {
      const int bt = blk >> 5, htt = blk & 31;
      const int bi = t & 15, cg = t >> 4;         // cg 0..63 = g*16 + j0
      const int j0 = cg & 15, g = cg >> 4;
      const int gc = g * 512 + htt * 16 + j0;
      const int r = t >> 6, ks = t & 63;          // staging: 1 float4/thread
      float4* Xs16 = (float4*)smem;               // [16][64] float4, swizzled
      float acc = 0.f;
      float4 pre = ((const float4*)(decbuf + (size_t)(bt * 16 + r) * 512))[ks];
#pragma unroll
      for (int kt = 0; kt < 4; ++kt) {
        __syncthreads();
        Xs16[r * 64 + (ks ^ (r & 7))] = pre;
        __syncthreads();
        if (kt < 3) {
          const float* src = (kt + 1 < 2) ? decbuf : hbuf;
          pre = ((const float4*)(src + (size_t)(bt * 16 + r) * 512 + ((kt + 1) & 1) * 256))[ks];
        }
        const float4* W4 = (const float4*)(((kt < 2) ? p.Wih : p.Whh) + (size_t)gc * 512 + (kt & 1) * 256);
#pragma unroll 8
        for (int k4 = 0; k4 < 64; ++k4) {
          float4 x = Xs16[bi * 64 + (k4 ^ (bi & 7))];
          float4 w = W4[k4];
          acc = fmaf(x.x, w.x, acc); acc = fmaf(x.y, w.y, acc);
          acc = fmaf(x.z, w.z, acc); acc = fmaf(x.w, w.w, acc);
        }
      }
      __syncthreads();
      float* gs = smem + 4096;                    // [16][65]
      gs[bi * 65 + cg] = acc + p.bih[gc] + p.bhh[gc];
      __syncthreads();
      if (t < 256) {
        const int j = t & 15, bi2 = t >> 4;
        float ig = gs[bi2 * 65 + j];
        float fg = gs[bi2 * 65 + 16 + j];
        float gg = gs[bi2 * 65 + 32 + j];
        float og = gs[bi2 * 65 + 48 + j];
        const int b = bt * 16 + bi2, h = htt * 16 + j;
        float cold = cbuf[b * 512 + h];
        float is = 1.f / (1.f + expf(-ig));
        float fs = 1.f / (1.f + expf(-fg));
        float os = 1.f / (1.f + expf(-og));
        float ct = fs * cold + is * tanhf(gg);
        float hl = os * tanhf(ct);
        cbuf[b * 512 + h] = ct;
        hlbuf[b * 512 + h] = hl;
      }
    }
    gsync(ub, ++tgt, blk);

    // ===== Island BCEF: one block per batch row b (blocks 128..255 idle) ====
    if (blk < Bn) {
      const int b = blk;
      float* hl_s    = smem;                 // 512
      float* hs_s    = smem + 512;           // 512
      float* inp_s   = smem + 1024;          // 512
      float* att_s   = smem + 1536;          // 256
      float* val_s   = smem + 1792;          // 256
      int*   idx_s   = (int*)(smem + 2048);  // 256
      float* alpha_s = smem + 2304;          // 256
      float* part2   = smem + 2560;          // 512
      float* partF   = smem + 3072;          // 512

      if (t < 128) ((float4*)hl_s)[t] = ((const float4*)(hlbuf + (size_t)b * 512))[t];
      __syncthreads();

      // --- B: inp = h_lstm @ Wa_in^T + ba_in (full-K sequential, R2 order) --
      if (t < 512) {
        const float4* xv = (const float4*)hl_s;      // broadcast reads
        const float4* Wr = (const float4*)(p.Wa_in + (size_t)t * 512);
        float acc = 0.f;
#pragma unroll 4
        for (int k4 = 0; k4 < 128; ++k4) {
          float4 x = xv[k4], w = Wr[k4];
          acc = fmaf(x.x, w.x, acc); acc = fmaf(x.y, w.y, acc);
          acc = fmaf(x.z, w.z, acc); acc = fmaf(x.w, w.w, acc);
        }
        inp_s[t] = acc + p.ba_in[t];
      }
      __syncthreads();

      // --- C: att[l] = sum_h V[h] tanh(inp+ctx), mask-skipped, R2-exact -----
      {
        const int wv = t >> 6, lane = t & 63;   // 16 waves x 16 l's each
        const float4* inp4 = (const float4*)inp_s;
        const float4* V4   = (const float4*)V_s;
        float4 i0 = inp4[lane],  i1 = inp4[64 + lane];
        float4 v0 = V4[lane],    v1 = V4[64 + lane];
        const float4* row = (const float4*)(ctx + ((size_t)b * 256 + (size_t)wv * 16) * 512);
        float4 c0 = row[lane], c1 = row[64 + lane];    // 1-ahead prefetch regs
        for (int i = 0; i < 16; ++i) {
          const int l = wv * 16 + i;
          float4 cc0 = c0, cc1 = c1;
          if (i < 15) {
            const float4* nr = row + (size_t)(i + 1) * 128;
            c0 = nr[lane]; c1 = nr[64 + lane];
          }
          if (mask_s[l] != 0.f) {                 // wave-uniform
            float a;
            a = v0.x * tanhf(i0.x + cc0.x);
            a = fmaf(v0.y, tanhf(i0.y + cc0.y), a);
            a = fmaf(v0.z, tanhf(i0.z + cc0.z), a);
            a = fmaf(v0.w, tanhf(i0.w + cc0.w), a);
            a = fmaf(v1.x, tanhf(i1.x + cc1.x), a);
            a = fmaf(v1.y, tanhf(i1.y + cc1.y), a);
            a = fmaf(v1.z, tanhf(i1.z + cc1.z), a);
            a = fmaf(v1.w, tanhf(i1.w + cc1.w), a);
#pragma unroll
            for (int off = 32; off > 0; off >>= 1) a += __shfl_xor(a, off, 64);
            if (lane == 0) att_s[l] = a;
          } else {
            if (lane == 0) att_s[l] = -INFINITY;
          }
        }
      }
      __syncthreads();

      // --- E: tree softmax + argmax + outputs + dec + hs (R2 bit-exact) ----
      {
        if (t < 256) { float a = att_s[t]; val_s[t] = a; idx_s[t] = t; }
        __syncthreads();
        for (int s = 128; s > 0; s >>= 1) {
          if (t < s) {
            float v1 = val_s[t], v2 = val_s[t + s];
            int   i1_ = idx_s[t], i2_ = idx_s[t + s];
            if (v2 > v1 || (v2 == v1 && i2_ < i1_)) { val_s[t] = v2; idx_s[t] = i2_; }
          }
          __syncthreads();
        }
        const float m = val_s[0];
        const int am = idx_s[0];
        __syncthreads();
        if (t < 256) {
          float e = expf(att_s[t] - m);   // exp(-inf)=0 for masked
          alpha_s[t] = e; val_s[t] = e;
        }
        __syncthreads();
        for (int s = 128; s > 0; s >>= 1) {
          if (t < s) val_s[t] += val_s[t + s];
          __syncthreads();
        }
        const float Z = val_s[0];
        __syncthreads();
        if (t < 256) alpha_s[t] = alpha_s[t] / Z;
        __syncthreads();
        if (t < 256) p.out[(size_t)b * Ln * Ln + (size_t)step * Ln + t] = alpha_s[t];
        if (t == 0) {
          p.out[OUT_PTR + (size_t)b * Ln + step] = (float)am;
          mask_s[am] = 0.f;
        }
        if (t < 512) decbuf[b * 512 + t] = p.emb[((size_t)(b * 256) + am) * 512 + t];
        // hs: 2 l-halves of 128 sequential each, pairwise combined (R2 order)
        const int hi = t & 255, lp = (t >> 8) & 1, ph2 = t >> 9;
        const int h = ph2 * 256 + hi;
        float acc = 0.f;
        {
          const float* cb = ctx + (size_t)b * 256 * 512 + h;
#pragma unroll 4
          for (int l = lp * 128; l < lp * 128 + 128; ++l) {
            float al = alpha_s[l];
            if (al != 0.f) acc = fmaf(al, cb[(size_t)l * 512], acc);
          }
        }
        if (lp == 1) part2[h] = acc;
        __syncthreads();
        if (lp == 0) hs_s[h] = acc + part2[h];
      }
      __syncthreads();

      // --- F: h = tanh([hs, hl] @ Who^T + bho), R2 pairwise K-split --------
      {
        const int o = t & 511, kh = t >> 9;
        const float4* xv = (const float4*)(kh ? hl_s : hs_s);  // broadcast
        const float4* Wr = (const float4*)(p.Who + (size_t)o * 1024 + (size_t)kh * 512);
        float acc = 0.f;
#pragma unroll 8
        for (int k4 = 0; k4 < 128; ++k4) {
          float4 x = xv[k4], w = Wr[k4];
          acc = fmaf(x.x, w.x, acc); acc = fmaf(x.y, w.y, acc);
          acc = fmaf(x.z, w.z, acc); acc = fmaf(x.w, w.w, acc);
        }
        if (kh == 1) partF[o] = acc;
        __syncthreads();
        if (kh == 0) hbuf[(size_t)b * 512 + o] = tanhf(acc + partF[o] + p.bho[o]);
      }
    }
    gsync(ub, ++tgt, blk);
  }

  // ---- epilogue: hF, cF ----
  {
    int idx = blk * 1024 + t;
    if (idx < Bn * Hn) {
      p.out[OUT_HF + idx] = hbuf[idx];
      p.out[OUT_CF + idx] = cbuf[idx];
    }
  }
}

extern "C" void kernel_launch(void* const* d_in, const int* in_sizes, int n_in,
                              void* d_out, int out_size, void* d_ws, size_t ws_size,
                              hipStream_t stream) {
  (void)in_sizes; (void)n_in; (void)out_size; (void)ws_size;
  const float* emb     = (const float*)d_in[0];
  const float* dec0    = (const float*)d_in[1];
  const float* h0      = (const float*)d_in[2];
  const float* c0      = (const float*)d_in[3];
  const float* context = (const float*)d_in[4];
  const float* Wih     = (const float*)d_in[5];
  const float* bih     = (const float*)d_in[6];
  const float* Whh     = (const float*)d_in[7];
  const float* bhh     = (const float*)d_in[8];
  const float* Who     = (const float*)d_in[9];
  const float* bho     = (const float*)d_in[10];
  const float* Wa_in   = (const float*)d_in[11];
  const float* ba_in   = (const float*)d_in[12];
  const float* Wa_ctx  = (const float*)d_in[13];
  const float* ba_ctx  = (const float*)d_in[14];
  const float* V       = (const float*)d_in[15];
  float* ws  = (float*)d_ws;
  float* out = (float*)d_out;

  hipMemsetAsync(d_ws, 0, 4096, stream);   // barrier words

  hipLaunchKernelGGL(ctx_precompute, dim3(4096), dim3(256), 0, stream,
                     context, Wa_ctx, ba_ctx, ws);

  PParams prm{emb, dec0, h0, c0, Wih, bih, Whh, bhh, Who, bho, Wa_in, ba_in, V, ws, out};
  void* args[] = {&prm};
  hipLaunchCooperativeKernel((const void*)pdecoder_main, dim3(256), dim3(1024),
                             args, 0, stream);
}

// Round 2
// 43937.512 us; speedup vs baseline: 1.0592x; 1.0592x over previous
//
#include <hip/hip_runtime.h>
#include <math.h>

namespace {
constexpr int Bn = 128, Ln = 256, En = 512, Hn = 512;

// ws layout (float offsets). First 8192 floats = barrier flags (256 x 64B) + gen.
constexpr long WS_CTX  = 8192;                       // [B][L][H] = ctx[b,l,o]
constexpr long WS_H    = WS_CTX + (long)Bn * Ln * Hn;
constexpr long WS_C    = WS_H   + (long)Bn * Hn;
constexpr long WS_HL   = WS_C   + (long)Bn * Hn;
constexpr long WS_INP  = WS_HL  + (long)Bn * Hn;
constexpr long WS_HS   = WS_INP + (long)Bn * Hn;
constexpr long WS_DEC  = WS_HS  + (long)Bn * Hn;
constexpr long WS_ATT  = WS_DEC + (long)Bn * En;
constexpr long WS_MASK = WS_ATT + (long)Bn * Ln;

// out layout (float offsets)
constexpr long OUT_PTR = (long)Bn * Ln * Ln;   // 8388608
constexpr long OUT_HF  = OUT_PTR + (long)Bn * Ln;
constexpr long OUT_CF  = OUT_HF + (long)Bn * Hn;
}

struct PParams {
  const float *emb, *dec0, *h0, *c0;
  const float *Wih, *bih, *Whh, *bhh;
  const float *Who, *bho, *Wa_in, *ba_in, *V;
  float *ws, *out;
};

// ---------- flag-array grid barrier (no RMW serialization) -------------------
// Arrival: blocks 1..255 each do ONE release-store to a private 64B-spaced
// flag (parallel, no line bouncing between arrivers). Block 0 polls all flags
// with 256 threads + __syncthreads_count, acquire-fences (syncs with every
// arriver's release), then release-stores the generation word. Waiters spin
// relaxed on gen (device-coherent) and do one acquire load after exit.
// Chain: arriver release(flag) -> blk0 acquire-fence -> blk0 release(gen)
//        -> waiter acquire(gen)  => all pre-barrier writes visible to all.
__device__ __forceinline__ void gsync(unsigned* ub, unsigned target, int blk) {
  __syncthreads();
  unsigned* flags = ub;            // flags[b] at ub[b*16] (64B apart)
  unsigned* gen   = ub + 4096;
  const int t = threadIdx.x;
  if (blk == 0) {
    for (;;) {
      unsigned v = (t > 0 && t < 256)
          ? __hip_atomic_load(&flags[t * 16], __ATOMIC_RELAXED, __HIP_MEMORY_SCOPE_AGENT)
          : target;
      int cnt = __syncthreads_count((int)(v >= target));
      if (cnt == (int)blockDim.x) break;
      __builtin_amdgcn_s_sleep(2);
    }
    __builtin_amdgcn_fence(__ATOMIC_ACQUIRE, "agent");
    if (t == 0)
      __hip_atomic_store(gen, target, __ATOMIC_RELEASE, __HIP_MEMORY_SCOPE_AGENT);
  } else {
    if (t == 0) {
      __hip_atomic_store(&flags[blk * 16], target, __ATOMIC_RELEASE, __HIP_MEMORY_SCOPE_AGENT);
      while (__hip_atomic_load(gen, __ATOMIC_RELAXED, __HIP_MEMORY_SCOPE_AGENT) < target)
        __builtin_amdgcn_s_sleep(2);
      (void)__hip_atomic_load(gen, __ATOMIC_ACQUIRE, __HIP_MEMORY_SCOPE_AGENT);
    }
  }
  __syncthreads();
}

// ---------------- ctx precompute: ctx[b,l,o] = context[b,l,:]·Wa_ctx[o,:] + ba_ctx[o]
__launch_bounds__(256)
__global__ void ctx_precompute(const float* __restrict__ context,
                               const float* __restrict__ Wa,
                               const float* __restrict__ ba,
                               float* __restrict__ ws) {
  __shared__ __align__(16) float As[16 * 68];
  __shared__ __align__(16) float Wsm[16 * 68];
  float* ctx = ws + WS_CTX;
  const int mt = blockIdx.x >> 3;
  const int nt = blockIdx.x & 7;
  const int t = threadIdx.x;
  const int tm = t & 15, tn = t >> 4;
  float acc00=0,acc01=0,acc02=0,acc03=0, acc10=0,acc11=0,acc12=0,acc13=0;
  float acc20=0,acc21=0,acc22=0,acc23=0, acc30=0,acc31=0,acc32=0,acc33=0;

  for (int kt = 0; kt < 32; ++kt) {
    __syncthreads();
    {
      const int m = t >> 2, k4 = t & 3;
      float4 a = *(const float4*)(context + (size_t)(mt * 64 + m) * 512 + kt * 16 + k4 * 4);
      As[(k4*4+0)*68 + m] = a.x; As[(k4*4+1)*68 + m] = a.y;
      As[(k4*4+2)*68 + m] = a.z; As[(k4*4+3)*68 + m] = a.w;
      float4 w = *(const float4*)(Wa + (size_t)(nt * 64 + m) * 512 + kt * 16 + k4 * 4);
      Wsm[(k4*4+0)*68 + m] = w.x; Wsm[(k4*4+1)*68 + m] = w.y;
      Wsm[(k4*4+2)*68 + m] = w.z; Wsm[(k4*4+3)*68 + m] = w.w;
    }
    __syncthreads();
#pragma unroll
    for (int k = 0; k < 16; ++k) {
      float4 a4 = *(const float4*)(As + k * 68 + tm * 4);
      float4 b4 = *(const float4*)(Wsm + k * 68 + tn * 4);
      acc00 = fmaf(a4.x, b4.x, acc00); acc01 = fmaf(a4.x, b4.y, acc01);
      acc02 = fmaf(a4.x, b4.z, acc02); acc03 = fmaf(a4.x, b4.w, acc03);
      acc10 = fmaf(a4.y, b4.x, acc10); acc11 = fmaf(a4.y, b4.y, acc11);
      acc12 = fmaf(a4.y, b4.z, acc12); acc13 = fmaf(a4.y, b4.w, acc13);
      acc20 = fmaf(a4.z, b4.x, acc20); acc21 = fmaf(a4.z, b4.y, acc21);
      acc22 = fmaf(a4.z, b4.z, acc22); acc23 = fmaf(a4.z, b4.w, acc23);
      acc30 = fmaf(a4.w, b4.x, acc30); acc31 = fmaf(a4.w, b4.y, acc31);
      acc32 = fmaf(a4.w, b4.z, acc32); acc33 = fmaf(a4.w, b4.w, acc33);
    }
  }
  const int col = nt * 64 + tn * 4;
  float4 bias = *(const float4*)(ba + col);
  float4 o0 = {acc00 + bias.x, acc01 + bias.y, acc02 + bias.z, acc03 + bias.w};
  float4 o1 = {acc10 + bias.x, acc11 + bias.y, acc12 + bias.z, acc13 + bias.w};
  float4 o2 = {acc20 + bias.x, acc21 + bias.y, acc22 + bias.z, acc23 + bias.w};
  float4 o3 = {acc30 + bias.x, acc31 + bias.y, acc32 + bias.z, acc33 + bias.w};
  const size_t base = (size_t)(mt * 64 + tm * 4) * 512 + col;
  *(float4*)(ctx + base + 0 * 512) = o0;
  *(float4*)(ctx + base + 1 * 512) = o1;
  *(float4*)(ctx + base + 2 * 512) = o2;
  *(float4*)(ctx + base + 3 * 512) = o3;
}

// --------- persistent main loop: 256 blocks x 1024 threads (1/CU, 16 waves) --
// 5 cheap barriers/step, every phase on all 256 blocks:
//   A (gates+LSTM) | B (inp) | C (att) | E (softmax/argmax/out/dec + hs) | F (h)
// All per-output fma sequences / trees / tie rules / K-splits are bit-exact
// clones of the passing R0 kernel; only thread/block assignment changed.
__launch_bounds__(1024, 4)
__global__ void pdecoder_main(PParams p) {
  __shared__ __align__(16) float smem[8192];   // 32 KB

  float* ws = p.ws;
  unsigned* ub = (unsigned*)ws;
  unsigned tgt = 0;
  const int t = threadIdx.x, blk = blockIdx.x;

  float* ctx    = ws + WS_CTX;
  float* hbuf   = ws + WS_H;
  float* cbuf   = ws + WS_C;
  float* hlbuf  = ws + WS_HL;
  float* inpbuf = ws + WS_INP;
  float* hsbuf  = ws + WS_HS;
  float* decbuf = ws + WS_DEC;
  float* attbuf = ws + WS_ATT;
  float* maskbuf= ws + WS_MASK;

  // ---- init state (ws poisoned every call) ----
  {
    int idx = blk * 1024 + t;
    if (idx < Bn * Hn) { hbuf[idx] = p.h0[idx]; cbuf[idx] = p.c0[idx]; }
    if (idx < Bn * En) decbuf[idx] = p.dec0[idx];
    if (idx < Bn * Ln) maskbuf[idx] = 1.0f;
  }
  gsync(ub, ++tgt, blk);

  for (int step = 0; step < Ln; ++step) {
    // ===== Phase A: gates = dec@Wih^T + h@Whh^T + b; LSTM elementwise =======
    // 256 blocks = 16 b-tiles(8) x 16 gc-tiles(128). One gate-output/thread;
    // K fully sequential (kt 0..3, k4 0..63, xyzw) — exact R0 per-output order.
    // Wave = 8 b-rows x 8 gate-cols: x reads are 8-distinct-address b128 with
    // 8-period XOR swizzle -> conflict-free broadcast; W reads 8-line dedup.
    {
      const int bt = blk >> 4, gt = blk & 15;
      const int bi = t & 7, cg = t >> 3;          // cg 0..127 = g*32 + j0
      const int j0 = cg & 31, g = cg >> 5;
      const int gc = g * 512 + gt * 32 + j0;
      const int r = t >> 6, ks = t & 63;          // staging (t<512): row, col
      float4* Xs = (float4*)smem;                 // [8][64] float4, swizzled
      float acc = 0.f;
      float4 pre;
      if (t < 512) pre = ((const float4*)(decbuf + (size_t)(bt * 8 + r) * 512))[ks];
#pragma unroll
      for (int kt = 0; kt < 4; ++kt) {
        __syncthreads();
        if (t < 512) Xs[r * 64 + (ks ^ r)] = pre;
        __syncthreads();
        if (t < 512 && kt < 3) {
          const float* src = (kt + 1 < 2) ? decbuf : hbuf;
          pre = ((const float4*)(src + (size_t)(bt * 8 + r) * 512 + ((kt + 1) & 1) * 256))[ks];
        }
        const float4* W4 = (const float4*)(((kt < 2) ? p.Wih : p.Whh) + (size_t)gc * 512 + (kt & 1) * 256);
#pragma unroll 8
        for (int k4 = 0; k4 < 64; ++k4) {
          float4 x = Xs[bi * 64 + (k4 ^ bi)];
          float4 w = W4[k4];
          acc = fmaf(x.x, w.x, acc); acc = fmaf(x.y, w.y, acc);
          acc = fmaf(x.z, w.z, acc); acc = fmaf(x.w, w.w, acc);
        }
      }
      __syncthreads();
      float* gs = smem + 4096;                    // [8][132]
      gs[bi * 132 + cg] = acc + p.bih[gc] + p.bhh[gc];
      __syncthreads();
      if (t < 256) {
        const int j = t & 31, bi2 = t >> 5;
        float ig = gs[bi2 * 132 + j];
        float fg = gs[bi2 * 132 + 32 + j];
        float gg = gs[bi2 * 132 + 64 + j];
        float og = gs[bi2 * 132 + 96 + j];
        const int b = bt * 8 + bi2, h = gt * 32 + j;
        float cold = cbuf[b * 512 + h];
        float is = 1.f / (1.f + expf(-ig));
        float fs = 1.f / (1.f + expf(-fg));
        float os = 1.f / (1.f + expf(-og));
        float ct = fs * cold + is * tanhf(gg);
        float hl = os * tanhf(ct);
        cbuf[b * 512 + h] = ct;
        hlbuf[b * 512 + h] = hl;
      }
    }
    gsync(ub, ++tgt, blk);

    // ===== Phase B: inp = h_lstm @ Wa_in^T + ba_in (full-K sequential) ======
    // 2 blocks per b, 256 o's each; hl broadcast from LDS (conflict-free).
    {
      const int b = blk >> 1, oh = blk & 1;
      float* hl_s = smem;
      if (t < 128) ((float4*)hl_s)[t] = ((const float4*)(hlbuf + (size_t)b * 512))[t];
      __syncthreads();
      if (t < 256) {
        const int o = oh * 256 + t;
        const float4* xv = (const float4*)hl_s;
        const float4* Wr = (const float4*)(p.Wa_in + (size_t)o * 512);
        float acc = 0.f;
#pragma unroll 4
        for (int k4 = 0; k4 < 128; ++k4) {
          float4 x = xv[k4], w = Wr[k4];
          acc = fmaf(x.x, w.x, acc); acc = fmaf(x.y, w.y, acc);
          acc = fmaf(x.z, w.z, acc); acc = fmaf(x.w, w.w, acc);
        }
        inpbuf[b * 512 + o] = acc + p.ba_in[o];
      }
    }
    gsync(ub, ++tgt, blk);

    // ===== Phase C: att[b,l] = sum_h V[h] tanh(inp+ctx), mask-skipped =======
    // (R0-verbatim: 2 blocks per b, 128 l each, 16 waves x 8 l.)
    {
      const int b = blk >> 1, ph = blk & 1;
      float* inp_s = smem;          // 512
      float* V_s   = smem + 512;    // 512
      if (t < 512) { inp_s[t] = inpbuf[b * 512 + t]; V_s[t] = p.V[t]; }
      __syncthreads();
      const int w = t >> 6, lane = t & 63;
      const float4* inp4 = (const float4*)inp_s;
      const float4* V4   = (const float4*)V_s;
      float4 i0 = inp4[lane],  i1 = inp4[64 + lane];
      float4 v0 = V4[lane],    v1 = V4[64 + lane];
      for (int i = 0; i < 8; ++i) {
        const int l = ph * 128 + w * 8 + i;
        float msk = maskbuf[b * 256 + l];      // wave-uniform
        if (msk == 0.f) {
          if (lane == 0) attbuf[b * 256 + l] = -INFINITY;
          continue;
        }
        const float4* row = (const float4*)(ctx + (size_t)(b * 256 + l) * 512);
        float4 c0 = row[lane], c1 = row[64 + lane];
        float a;
        a = v0.x * tanhf(i0.x + c0.x);
        a = fmaf(v0.y, tanhf(i0.y + c0.y), a);
        a = fmaf(v0.z, tanhf(i0.z + c0.z), a);
        a = fmaf(v0.w, tanhf(i0.w + c0.w), a);
        a = fmaf(v1.x, tanhf(i1.x + c1.x), a);
        a = fmaf(v1.y, tanhf(i1.y + c1.y), a);
        a = fmaf(v1.z, tanhf(i1.z + c1.z), a);
        a = fmaf(v1.w, tanhf(i1.w + c1.w), a);
#pragma unroll
        for (int off = 32; off > 0; off >>= 1) a += __shfl_xor(a, off, 64);
        if (lane == 0) attbuf[b * 256 + l] = a;
      }
    }
    gsync(ub, ++tgt, blk);

    // ===== Phase E: tree softmax + argmax + outputs + hs (R0 bit-exact) =====
    {
      const int b = blk >> 1, ph = blk & 1;
      float* att_s   = smem;               // 256
      float* val_s   = smem + 256;         // 256
      int*   idx_s   = (int*)(smem + 512); // 256
      float* alpha_s = smem + 768;         // 256
      float* part_s  = smem + 1024;        // 256
      if (t < 256) {
        float a = attbuf[b * 256 + t];
        att_s[t] = a; val_s[t] = a; idx_s[t] = t;
      }
      __syncthreads();
      for (int s = 128; s > 0; s >>= 1) {
        if (t < s) {
          float v1 = val_s[t], v2 = val_s[t + s];
          int   i1 = idx_s[t], i2 = idx_s[t + s];
          if (v2 > v1 || (v2 == v1 && i2 < i1)) { val_s[t] = v2; idx_s[t] = i2; }
        }
        __syncthreads();
      }
      const float m = val_s[0];
      const int am = idx_s[0];
      __syncthreads();
      if (t < 256) {
        float e = expf(att_s[t] - m);   // exp(-inf)=0 for masked
        alpha_s[t] = e; val_s[t] = e;
      }
      __syncthreads();
      for (int s = 128; s > 0; s >>= 1) {
        if (t < s) val_s[t] += val_s[t + s];
        __syncthreads();
      }
      const float Z = val_s[0];
      __syncthreads();
      if (t < 256) alpha_s[t] = alpha_s[t] / Z;
      __syncthreads();
      if (ph == 0) {
        if (t < 256) p.out[(size_t)b * Ln * Ln + (size_t)step * Ln + t] = alpha_s[t];
        if (t == 0) {
          p.out[OUT_PTR + (size_t)b * Ln + step] = (float)am;
          maskbuf[b * 256 + am] = 0.f;
        }
        if (t < 512) decbuf[b * 512 + t] = p.emb[((size_t)(b * 256) + am) * 512 + t];
      }
      // hs[b, ph*256 + hi] = sum_l alpha[l] * ctx[b,l,h] — R0 order (2 l-halves
      // of 128 sequential each, pairwise combined). alpha==0 skip is bitwise
      // neutral: fmaf(0,c,acc)==acc (acc starts +0, never -0).
      const int hi = t & 255, lp = (t >> 8) & 1;
      const int h = ph * 256 + hi;
      float acc = 0.f;
      if (t < 512) {
        const float* cb = ctx + (size_t)b * 256 * 512 + h;
#pragma unroll 4
        for (int l = lp * 128; l < lp * 128 + 128; ++l) {
          float al = alpha_s[l];
          if (al != 0.f) acc = fmaf(al, cb[(size_t)l * 512], acc);
        }
      }
      if (t < 512 && lp == 1) part_s[hi] = acc;
      __syncthreads();
      if (t < 512 && lp == 0) hsbuf[(size_t)b * 512 + h] = acc + part_s[hi];
    }
    gsync(ub, ++tgt, blk);

    // ===== Phase F: h = tanh([hs, hl] @ Who^T + bho) — pairwise K-split =====
    // 2 blocks per b, 256 o's each; kh=0 -> hs-half, kh=1 -> hl-half (R0 map),
    // each half-K sequential, combined (acc0+acc1)+bho then tanhf (R0 order).
    {
      const int b = blk >> 1, oh = blk & 1;
      float* hs_s  = smem;           // 512
      float* hl_s  = smem + 512;     // 512
      float* partF = smem + 1024;    // 256
      if (t < 128) {
        ((float4*)hs_s)[t] = ((const float4*)(hsbuf + (size_t)b * 512))[t];
        ((float4*)hl_s)[t] = ((const float4*)(hlbuf + (size_t)b * 512))[t];
      }
      __syncthreads();
      float acc = 0.f;
      if (t < 512) {
        const int oj = t & 255, kh = t >> 8;
        const int o = oh * 256 + oj;
        const float4* xv = (const float4*)(kh ? hl_s : hs_s);
        const float4* Wr = (const float4*)(p.Who + (size_t)o * 1024 + (size_t)kh * 512);
#pragma unroll 4
        for (int k4 = 0; k4 < 128; ++k4) {
          float4 x = xv[k4], w = Wr[k4];
          acc = fmaf(x.x, w.x, acc); acc = fmaf(x.y, w.y, acc);
          acc = fmaf(x.z, w.z, acc); acc = fmaf(x.w, w.w, acc);
        }
        if (kh == 1) partF[oj] = acc;
      }
      __syncthreads();
      if (t < 256) {
        const int o = oh * 256 + t;
        hbuf[(size_t)b * 512 + o] = tanhf(acc + partF[t] + p.bho[o]);
      }
    }
    gsync(ub, ++tgt, blk);
  }

  // ---- epilogue: hF, cF ----
  {
    int idx = blk * 1024 + t;
    if (idx < Bn * Hn) {
      p.out[OUT_HF + idx] = hbuf[idx];
      p.out[OUT_CF + idx] = cbuf[idx];
    }
  }
}

extern "C" void kernel_launch(void* const* d_in, const int* in_sizes, int n_in,
                              void* d_out, int out_size, void* d_ws, size_t ws_size,
                              hipStream_t stream) {
  (void)in_sizes; (void)n_in; (void)out_size; (void)ws_size;
  const float* emb     = (const float*)d_in[0];
  const float* dec0    = (const float*)d_in[1];
  const float* h0      = (const float*)d_in[2];
  const float* c0      = (const float*)d_in[3];
  const float* context = (const float*)d_in[4];
  const float* Wih     = (const float*)d_in[5];
  const float* bih     = (const float*)d_in[6];
  const float* Whh     = (const float*)d_in[7];
  const float* bhh     = (const float*)d_in[8];
  const float* Who     = (const float*)d_in[9];
  const float* bho     = (const float*)d_in[10];
  const float* Wa_in   = (const float*)d_in[11];
  const float* ba_in   = (const float*)d_in[12];
  const float* Wa_ctx  = (const float*)d_in[13];
  const float* ba_ctx  = (const float*)d_in[14];
  const float* V       = (const float*)d_in[15];
  float* ws  = (float*)d_ws;
  float* out = (float*)d_out;

  hipMemsetAsync(d_ws, 0, 32768, stream);   // barrier flags + gen

  hipLaunchKernelGGL(ctx_precompute, dim3(4096), dim3(256), 0, stream,
                     context, Wa_ctx, ba_ctx, ws);

  PParams prm{emb, dec0, h0, c0, Wih, bih, Whh, bhh, Who, bho, Wa_in, ba_in, V, ws, out};
  void* args[] = {&prm};
  hipLaunchCooperativeKernel((const void*)pdecoder_main, dim3(256), dim3(1024),
                             args, 0, stream);
}